// Round 13
// baseline (192.793 us; speedup 1.0000x reference)
//
#include <hip/hip_runtime.h>
#include <math.h>

#define NE   8192
#define ED   512
#define BB   8
#define TT   1024
#define MM   (BB*TT)

#define FLT_BIG 3.402823466e38f
#define MARGIN  0.08f

typedef _Float16 half8 __attribute__((ext_vector_type(8)));
typedef _Float16 half4 __attribute__((ext_vector_type(4)));
typedef float    floatx4 __attribute__((ext_vector_type(4)));

typedef __attribute__((address_space(3))) unsigned int       lds_u32;
typedef const __attribute__((address_space(1))) unsigned int gbl_u32;

__device__ __forceinline__ void async_copy16(void* lds, const void* g) {
    __builtin_amdgcn_global_load_lds((gbl_u32*)(unsigned long long)g,
                                     (lds_u32*)(unsigned long long)lds,
                                     16, 0, 0);
}

// ---------------------------------------------------------------------------
// K0 (fused prep): blocks 0..1023 transpose z -> Zh (f16 4z) + Zt (fp32 rows);
// blocks 1024..5375 convert emb/pw -> hi/lo f16; blocks 5376..5384 zero
// cnorm (+legacy scalars). (bmin needs NO init: refine only reads the
// domain-valid unit slice, which valid coarse blocks always write.)
// ---------------------------------------------------------------------------
__global__ __launch_bounds__(256) void k_prep(
    const float* __restrict__ z, const float* __restrict__ emb,
    const float* __restrict__ pw, _Float16* __restrict__ Zh,
    float* __restrict__ Zt, _Float16* __restrict__ Eb,
    _Float16* __restrict__ Wb, float* __restrict__ cnorm)
{
    const int bid = blockIdx.x;
    const int tid = threadIdx.x;
    if (bid < 1024) {
        __shared__ float T[64][68];
        const int ct = bid & 7, tt = (bid >> 3) & 15, b = bid >> 7;
        const int f4 = tid & 15;
        const int c0 = tid >> 4;
#pragma unroll
        for (int r = 0; r < 4; ++r) {
            const int c = c0 + r * 16;
            const float4 v = *(const float4*)(z + ((size_t)(b * ED + ct * 64 + c)) * TT + tt * 64 + f4 * 4);
            T[f4*4+0][c] = v.x; T[f4*4+1][c] = v.y;
            T[f4*4+2][c] = v.z; T[f4*4+3][c] = v.w;
        }
        __syncthreads();
        {   // f16 hi write
            const int tl = tid >> 2, q = tid & 3;
            const size_t m = (size_t)b * TT + tt * 64 + tl;
            _Float16* outh = Zh + m * 512 + ct * 64 + q * 16;
#pragma unroll
            for (int g = 0; g < 2; ++g) {
                half8 hv;
#pragma unroll
                for (int jj = 0; jj < 8; ++jj)
                    hv[jj] = (_Float16)(4.0f * T[tl][q*16 + g*8 + jj]);
                *(half8*)(outh + g * 8) = hv;
            }
        }
        {   // fp32 transposed write
            const int tl2 = tid >> 4;
            const int c4 = (tid & 15) * 4;
#pragma unroll
            for (int it = 0; it < 4; ++it) {
                const int t_local = tl2 + it * 16;
                const float4 v = *(const float4*)&T[t_local][c4];
                *(float4*)(Zt + ((size_t)b * TT + tt * 64 + t_local) * 512 + ct * 64 + c4) = v;
            }
        }
    } else if (bid < 5376) {
        const int g = (bid - 1024) * 256 + tid;
        const int row = g >> 7, c4 = (g & 127) * 4;
        const float* src;
        _Float16* dst;
        if (row < NE) { src = emb + (size_t)row * 512;        dst = Eb + (size_t)row * 1024; }
        else          { src = pw + (size_t)(row - NE) * 512;  dst = Wb + (size_t)(row - NE) * 1024; }
        const float4 v = *(const float4*)(src + c4);
        half4 h, l;
        const float s[4] = {v.x * 64.0f, v.y * 64.0f, v.z * 64.0f, v.w * 64.0f};
#pragma unroll
        for (int j = 0; j < 4; ++j) {
            const _Float16 hh = (_Float16)s[j];
            h[j] = hh;
            l[j] = (_Float16)(s[j] - (float)hh);
        }
        *(half4*)(dst + c4) = h;
        *(half4*)(dst + 512 + c4) = l;
    } else {
        const int zidx = bid - 5376;          // 0..8
        if (zidx < 8) {
            ((float4*)cnorm)[zidx * 256 + tid] = make_float4(0.f, 0.f, 0.f, 0.f);
        } else if (tid == 0) {
            cnorm[NE] = 0.0f;
            ((unsigned int*)cnorm)[NE + 1] = 0u;
        }
    }
}

// ---------------------------------------------------------------------------
// K1: codebook GEMM, fused-term staging (Eh,El,Wh,Wl loaded once per 64-k
// chunk; 3 hi/lo MFMA terms). 128n x 64d tiles, 256 threads.
// NEW: Eb-LOCALITY XCD REMAP -- grid linearized to 512; the 8 blocks sharing
// an Eb panel (same n0, all 8 d0) get ids L = r+8k within a 64-id window ->
// same XCD (round-robin dispatch), 8 consecutive rounds -> the 272KB panel
// is fetched once into that XCD's L2 and hit 7x (Eb HBM traffic ~136->17MB).
// Wb (1MB) stays L2-hot. Bijective: n0-tile=(L>>6)*8+(L&7), d0-tile=(L>>3)&7.
// ---------------------------------------------------------------------------
#define S_AH 0
#define S_AL 8192
#define S_BH 16384
#define S_BL 20480
__global__ __launch_bounds__(256) void k_cb(
    const _Float16* __restrict__ Eb, const _Float16* __restrict__ Wb,
    const float* __restrict__ pb, float* __restrict__ cb,
    _Float16* __restrict__ Ch, float* __restrict__ cnorm)
{
    __shared__ __align__(16) _Float16 S[24576];   // Ah(16K)|Al(16K)|Bh(8K)|Bl(8K) bytes

    const int tid = threadIdx.x;
    const int wave = tid >> 6, lane = tid & 63;
    const int L = blockIdx.x;
    const int n0 = (((L >> 6) * 8) + (L & 7)) * 128;
    const int d0 = ((L >> 3) & 7) * 64;
    const int wm = wave >> 1, wn = wave & 1;      // 2x2 waves -> 64 codes x 32 d
    const int lm = lane & 15, lq = lane >> 4;

    floatx4 acc[4][2];
#pragma unroll
    for (int i = 0; i < 4; ++i)
#pragma unroll
        for (int j = 0; j < 2; ++j) acc[i][j] = (floatx4)0.0f;

    for (int lc = 0; lc < 8; ++lc) {
        const int kc = lc * 64;
        __syncthreads();
#pragma unroll
        for (int r = 0; r < 12; ++r) {            // 48 spans of 1KB
            const int s = wave * 12 + r;
            const int row8 = lane >> 3;
            const int srcx = lane & 7;
            if (s < 16) {
                const int row = s * 8 + row8;
                const int src = srcx ^ (row & 7);
                async_copy16(&S[S_AH + s * 512], Eb + (size_t)(n0 + row) * 1024 + kc + src * 8);
            } else if (s < 32) {
                const int s2 = s - 16;
                const int row = s2 * 8 + row8;
                const int src = srcx ^ (row & 7);
                async_copy16(&S[S_AL + s2 * 512], Eb + (size_t)(n0 + row) * 1024 + 512 + kc + src * 8);
            } else if (s < 40) {
                const int s2 = s - 32;
                const int row = s2 * 8 + row8;
                const int src = srcx ^ (row & 7);
                async_copy16(&S[S_BH + s2 * 512], Wb + (size_t)(d0 + row) * 1024 + kc + src * 8);
            } else {
                const int s2 = s - 40;
                const int row = s2 * 8 + row8;
                const int src = srcx ^ (row & 7);
                async_copy16(&S[S_BL + s2 * 512], Wb + (size_t)(d0 + row) * 1024 + 512 + kc + src * 8);
            }
        }
        __syncthreads();

#pragma unroll
        for (int ks = 0; ks < 2; ++ks) {
            half8 ah[4], al[4], bh[2], bl[2];
#pragma unroll
            for (int i = 0; i < 4; ++i) {
                const int row = wm * 64 + i * 16 + lm;
                const int slot = (ks * 4 + lq) ^ (row & 7);
                ah[i] = *(const half8*)&S[S_AH + row * 64 + slot * 8];
                al[i] = *(const half8*)&S[S_AL + row * 64 + slot * 8];
            }
#pragma unroll
            for (int j = 0; j < 2; ++j) {
                const int row = wn * 32 + j * 16 + lm;
                const int slot = (ks * 4 + lq) ^ (row & 7);
                bh[j] = *(const half8*)&S[S_BH + row * 64 + slot * 8];
                bl[j] = *(const half8*)&S[S_BL + row * 64 + slot * 8];
            }
#pragma unroll
            for (int i = 0; i < 4; ++i)
#pragma unroll
                for (int j = 0; j < 2; ++j) {
                    acc[i][j] = __builtin_amdgcn_mfma_f32_16x16x32_f16(ah[i], bh[j], acc[i][j], 0, 0, 0);
                    acc[i][j] = __builtin_amdgcn_mfma_f32_16x16x32_f16(ah[i], bl[j], acc[i][j], 0, 0, 0);
                    acc[i][j] = __builtin_amdgcn_mfma_f32_16x16x32_f16(al[i], bh[j], acc[i][j], 0, 0, 0);
                }
        }
    }

    float bias[2];
#pragma unroll
    for (int j = 0; j < 2; ++j) bias[j] = pb[d0 + wn * 32 + j * 16 + lm];

    float nsum[16];
#pragma unroll
    for (int p = 0; p < 16; ++p) nsum[p] = 0.0f;

#pragma unroll
    for (int i = 0; i < 4; ++i) {
#pragma unroll
        for (int j = 0; j < 2; ++j) {
            const int d = d0 + wn * 32 + j * 16 + lm;
#pragma unroll
            for (int r = 0; r < 4; ++r) {
                const float v = acc[i][j][r] * 0.000244140625f + bias[j];  // 1/4096
                const int n = n0 + wm * 64 + i * 16 + lq * 4 + r;
                cb[(size_t)n * 512 + d] = v;
                Ch[(size_t)n * 512 + d] = (_Float16)(v * 64.0f);
                nsum[i * 4 + r] += v * v;
            }
        }
    }
#pragma unroll
    for (int stp = 1; stp < 16; stp <<= 1) {
#pragma unroll
        for (int p = 0; p < 16; ++p) nsum[p] += __shfl_xor(nsum[p], stp);
    }
    float myv = nsum[0];
#pragma unroll
    for (int p = 1; p < 16; ++p) if (lm == p) myv = nsum[p];
    const int n = n0 + wm * 64 + (lm >> 2) * 16 + lq * 4 + (lm & 3);
    atomicAdd(&cnorm[n], myv);
}

// ---------------------------------------------------------------------------
// K2: coarse distance GEMM (hi-only, K=512). ROUND-3/10 VERBATIM. Counted-
// vmcnt 2-phase, XCD swizzle, setprio. Invalid blocks return without
// writing; bs aliases As[0].
// ---------------------------------------------------------------------------
__global__ __launch_bounds__(256) void k_coarse(
    const _Float16* __restrict__ Zh, const _Float16* __restrict__ Ch,
    const float* __restrict__ cnorm, const int* __restrict__ dom_arr,
    _Float16* __restrict__ bmin)
{
    const int f   = blockIdx.y * 64 + blockIdx.x;
    const int xcd = f & 7;
    const int idx = f >> 3;
    const int mt  = idx >> 3;                 // z-tile 0..63
    const int nt  = (idx & 7) * 8 + xcd;      // code-tile 0..63
    const int b = mt >> 3;
    const int dom = dom_arr[b];
    const int chunk = nt >> 4;
    const bool valid = (dom == 3) || (dom == 0 && chunk == 0) ||
                       (dom == 1 && chunk == 1) || (dom == 2 && chunk >= 2);
    if (!valid) return;

    const int tid = threadIdx.x;
    const int m0 = mt * 128, n0 = nt * 128;

    __shared__ __align__(16) _Float16 As[2][128 * 64];   // codes (As[0] reused as bs)
    __shared__ __align__(16) _Float16 Bs[2][128 * 64];   // z
    __shared__ __align__(16) float cnLds[128];

    const int wave = tid >> 6, lane = tid & 63;
    const int wm = wave >> 1, wn = wave & 1;   // wm: code rows, wn: z cols
    const int lm = lane & 15, lq = lane >> 4;

    floatx4 acc[4][4];
#pragma unroll
    for (int i = 0; i < 4; ++i)
#pragma unroll
        for (int j = 0; j < 4; ++j) acc[i][j] = (floatx4)0.0f;

#define STAGE_K(buf, lc_) do {                                                  \
        const int kk0_ = (lc_) * 64;                                            \
        _Pragma("unroll")                                                       \
        for (int r_ = 0; r_ < 4; ++r_) {                                        \
            const int s_ = wave * 4 + r_;                                       \
            const int row_ = s_ * 8 + (lane >> 3);                              \
            const int src_ = (lane & 7) ^ (row_ & 7);                           \
            async_copy16(&As[buf][s_ * 512], Ch + (size_t)(n0 + row_) * 512 + kk0_ + src_ * 8); \
            async_copy16(&Bs[buf][s_ * 512], Zh + (size_t)(m0 + row_) * 512 + kk0_ + src_ * 8); \
        } } while (0)

    STAGE_K(0, 0);
    if (wave == 0 && lane < 32)
        async_copy16(&cnLds[0], cnorm + n0 + lane * 4);

    for (int lc = 0; lc < 8; ++lc) {
        const int cur = lc & 1;
        if (lc < 7) {
            STAGE_K(cur ^ 1, lc + 1);   // 8 more loads in flight (16 outstanding)
            asm volatile("s_waitcnt vmcnt(8)" ::: "memory");
        } else {
            asm volatile("s_waitcnt vmcnt(0)" ::: "memory");
        }
        __builtin_amdgcn_s_barrier();    // all waves' chunk-lc loads landed
        asm volatile("" ::: "memory");

        __builtin_amdgcn_s_setprio(1);
#pragma unroll
        for (int ks = 0; ks < 2; ++ks) {
            half8 af[4], bf[4];
#pragma unroll
            for (int i = 0; i < 4; ++i) {
                const int row = wm * 64 + i * 16 + lm;            // code row
                const int slot = (ks * 4 + lq) ^ (row & 7);
                af[i] = *(const half8*)&As[cur][row * 64 + slot * 8];
            }
#pragma unroll
            for (int j = 0; j < 4; ++j) {
                const int row = wn * 64 + j * 16 + lm;            // z row
                const int slot = (ks * 4 + lq) ^ (row & 7);
                bf[j] = *(const half8*)&Bs[cur][row * 64 + slot * 8];
            }
#pragma unroll
            for (int i = 0; i < 4; ++i)
#pragma unroll
                for (int j = 0; j < 4; ++j)
                    acc[i][j] = __builtin_amdgcn_mfma_f32_16x16x32_f16(af[i], bf[j], acc[i][j], 0, 0, 0);
        }
        __builtin_amdgcn_s_setprio(0);
        asm volatile("" ::: "memory");
        __builtin_amdgcn_s_barrier();    // all waves done READING buf[cur]
    }
#undef STAGE_K

    // D layout: row (code) = wm*64 + i*16 + lq*4 + r, col (z) = wn*64 + j*16 + lm
    float cnv[4][4];
#pragma unroll
    for (int i = 0; i < 4; ++i)
#pragma unroll
        for (int r = 0; r < 4; ++r)
            cnv[i][r] = cnLds[wm * 64 + i * 16 + lq * 4 + r];

    // 4-code unit minima: fully in-lane over the r-quad
    float um[4][4];
#pragma unroll
    for (int i = 0; i < 4; ++i) {
#pragma unroll
        for (int j = 0; j < 4; ++j) {
            float m01 = fminf(cnv[i][0] - acc[i][j][0] * 0.0078125f,
                              cnv[i][1] - acc[i][j][1] * 0.0078125f);
            float m23 = fminf(cnv[i][2] - acc[i][j][2] * 0.0078125f,
                              cnv[i][3] - acc[i][j][3] * 0.0078125f);
            um[i][j] = fminf(m01, m23);
        }
    }

    // loop-final barrier already separates all As reads from this aliasing write
    _Float16 (*bs)[40] = (_Float16(*)[40])&As[0][0];   // [m_local][unit 0..31]
#pragma unroll
    for (int i = 0; i < 4; ++i)
#pragma unroll
        for (int j = 0; j < 4; ++j)
            bs[wn * 64 + j * 16 + lm][wm * 16 + i * 4 + lq] = (_Float16)um[i][j];
    __syncthreads();
    {   // writeout: 128 rows x 32 units
        const int r = tid >> 1, h = tid & 1;
        half8 v0, v1;
#pragma unroll
        for (int k = 0; k < 8; ++k) { v0[k] = bs[r][h * 16 + k]; v1[k] = bs[r][h * 16 + 8 + k]; }
        _Float16* dst = bmin + (size_t)(m0 + r) * 2048 + nt * 32 + h * 16;
        *(half8*)dst = v0;
        *(half8*)(dst + 8) = v1;
    }
}

// ---------------------------------------------------------------------------
// K3: refine (r12 structure). One wave per z-row, no block barrier.
// Register-resident um via unrolled-with-guard loops; LDS candidate queue
// (ballot+rank, original (g,j,L) order); pairwise rescore with 8 parallel
// FMA/shuffle chains. Lane 0 writes rowloss[m] = bestv + ||z||^2.
// ---------------------------------------------------------------------------
__global__ __launch_bounds__(256) void k_refine(
    const float* __restrict__ Zt, const float* __restrict__ cb,
    const float* __restrict__ cnorm, const _Float16* __restrict__ bmin,
    const int* __restrict__ dom_arr, int* __restrict__ minidx,
    float* __restrict__ out_idx, float* __restrict__ rowloss)
{
    __shared__ unsigned short queue[4][2048];
    const int wv = threadIdx.x >> 6;
    const int m = blockIdx.x * 4 + wv;
    const int lane = threadIdx.x & 63;
    const int b = m >> 10;
    const int dom = dom_arr[b];
    const int bg = (dom == 0) ? 0 : (dom == 1) ? 1 : (dom == 2) ? 2 : 0;
    const int ng = (dom == 2) ? 2 : (dom == 3) ? 4 : 1;

    const _Float16* brow = bmin + (size_t)m * 2048;
    float um[4][8];
#pragma unroll
    for (int g = 0; g < 4; ++g) {
        if (g < ng) {
            const half8 u = *(const half8*)(brow + (bg + g) * 512 + lane * 8);
#pragma unroll
            for (int j = 0; j < 8; ++j) um[g][j] = (float)u[j];
        }
    }

    float gmin = FLT_BIG;
#pragma unroll
    for (int g = 0; g < 4; ++g) {
        if (g < ng) {
#pragma unroll
            for (int j = 0; j < 8; ++j) gmin = fminf(gmin, um[g][j]);
        }
    }
#pragma unroll
    for (int s = 32; s > 0; s >>= 1) gmin = fminf(gmin, __shfl_xor(gmin, s));
    const float thr = gmin + MARGIN;

    float zr[8];
#pragma unroll
    for (int j = 0; j < 8; ++j)
        zr[j] = Zt[(size_t)m * 512 + lane + 64 * j];

    // ||z_row||^2 (wave-uniform after butterfly) for the loss
    float rss = 0.f;
#pragma unroll
    for (int j = 0; j < 8; ++j) rss += zr[j] * zr[j];
#pragma unroll
    for (int s = 32; s > 0; s >>= 1) rss += __shfl_xor(rss, s);

    // build candidate queue; order == original (g, j, L-ascending)
    unsigned short* q = &queue[wv][0];
    const unsigned long long lanemask_lt = (lane == 0) ? 0ull : (~0ull >> (64 - lane));
    int cnt = 0;
#pragma unroll
    for (int g = 0; g < 4; ++g) {
        if (g < ng) {
#pragma unroll
            for (int j = 0; j < 8; ++j) {
                const bool hit = (um[g][j] <= thr);
                const unsigned long long mask = __ballot(hit);
                if (hit) {
                    const int rank = __popcll(mask & lanemask_lt);
                    q[cnt + rank] = (unsigned short)((bg + g) * 512 + lane * 8 + j);
                }
                cnt += __popcll(mask);
            }
        }
    }

    float bestv = FLT_BIG; int besti = 0x7FFFFFFF;

    for (int ci = 0; ci < cnt; ci += 2) {
        const int u0 = q[ci];
        const bool has1 = (ci + 1 < cnt);
        const int u1 = has1 ? (int)q[ci + 1] : 0;
        const int nb0 = u0 * 4, nb1 = u1 * 4;
        const float* r0 = cb + (size_t)nb0 * 512 + lane;
        const float* r1 = cb + (size_t)nb1 * 512 + lane;

        float a0 = 0.f, a1 = 0.f, a2 = 0.f, a3 = 0.f;
        float c0 = 0.f, c1 = 0.f, c2 = 0.f, c3 = 0.f;
#pragma unroll
        for (int jj = 0; jj < 8; ++jj) {
            const int o = 64 * jj;
            a0 += zr[jj] * r0[o];
            a1 += zr[jj] * r0[512 + o];
            a2 += zr[jj] * r0[1024 + o];
            a3 += zr[jj] * r0[1536 + o];
        }
        if (has1) {
#pragma unroll
            for (int jj = 0; jj < 8; ++jj) {
                const int o = 64 * jj;
                c0 += zr[jj] * r1[o];
                c1 += zr[jj] * r1[512 + o];
                c2 += zr[jj] * r1[1024 + o];
                c3 += zr[jj] * r1[1536 + o];
            }
        }
#pragma unroll
        for (int s = 32; s > 0; s >>= 1) {
            a0 += __shfl_xor(a0, s); a1 += __shfl_xor(a1, s);
            a2 += __shfl_xor(a2, s); a3 += __shfl_xor(a3, s);
            c0 += __shfl_xor(c0, s); c1 += __shfl_xor(c1, s);
            c2 += __shfl_xor(c2, s); c3 += __shfl_xor(c3, s);
        }
        {
            const float f0 = cnorm[nb0]     - 2.0f * a0;
            const float f1 = cnorm[nb0 + 1] - 2.0f * a1;
            const float f2 = cnorm[nb0 + 2] - 2.0f * a2;
            const float f3 = cnorm[nb0 + 3] - 2.0f * a3;
            if (f0 < bestv || (f0 == bestv && nb0     < besti)) { bestv = f0; besti = nb0;     }
            if (f1 < bestv || (f1 == bestv && nb0 + 1 < besti)) { bestv = f1; besti = nb0 + 1; }
            if (f2 < bestv || (f2 == bestv && nb0 + 2 < besti)) { bestv = f2; besti = nb0 + 2; }
            if (f3 < bestv || (f3 == bestv && nb0 + 3 < besti)) { bestv = f3; besti = nb0 + 3; }
        }
        if (has1) {
            const float f0 = cnorm[nb1]     - 2.0f * c0;
            const float f1 = cnorm[nb1 + 1] - 2.0f * c1;
            const float f2 = cnorm[nb1 + 2] - 2.0f * c2;
            const float f3 = cnorm[nb1 + 3] - 2.0f * c3;
            if (f0 < bestv || (f0 == bestv && nb1     < besti)) { bestv = f0; besti = nb1;     }
            if (f1 < bestv || (f1 == bestv && nb1 + 1 < besti)) { bestv = f1; besti = nb1 + 1; }
            if (f2 < bestv || (f2 == bestv && nb1 + 2 < besti)) { bestv = f2; besti = nb1 + 2; }
            if (f3 < bestv || (f3 == bestv && nb1 + 3 < besti)) { bestv = f3; besti = nb1 + 3; }
        }
    }
    if (lane == 0) {
        minidx[m] = besti;
        out_idx[m] = (float)besti;
        rowloss[m] = bestv + rss;   // exact ||c-z||^2 for this row
    }
}

// ---------------------------------------------------------------------------
// K4: z_q gather + transpose via LDS (coalesced cb reads, coalesced outz
// writes; LDS pitch 129 -> conflict-free). Block (0,0,0) reduces
// rowloss[8192] -> outloss.
// ---------------------------------------------------------------------------
__global__ __launch_bounds__(256) void k_zq(
    const float* __restrict__ cb, const int* __restrict__ minidx,
    const float* __restrict__ rowloss, float* __restrict__ outz,
    float* __restrict__ outloss)
{
    __shared__ float Tz[64][129];
    const int cc = blockIdx.x, tt = blockIdx.y, b = blockIdx.z;
    const int lane = threadIdx.x & 63;
    const int w = threadIdx.x >> 6;

    // stage: wave w loads rows w*16..w*16+15, each row slice coalesced
#pragma unroll 4
    for (int r = 0; r < 16; ++r) {
        const int row = w * 16 + r;
        const int idx = minidx[b * TT + tt * 64 + row];      // wave-uniform
        const float2 v = *(const float2*)(cb + (size_t)idx * 512 + cc * 128 + lane * 2);
        Tz[row][lane * 2]     = v.x;
        Tz[row][lane * 2 + 1] = v.y;
    }
    __syncthreads();

    // write: lanes sweep t (contiguous per instr); 32 c's per thread
    const int t = tt * 64 + lane;
#pragma unroll 8
    for (int k = 0; k < 32; ++k) {
        const int cl = w * 32 + k;
        outz[((size_t)(b * ED + cc * 128 + cl)) * TT + t] = Tz[lane][cl];
    }

    if (cc == 0 && tt == 0 && b == 0) {
        __shared__ float red[4];
        float s = 0.f;
#pragma unroll
        for (int k = 0; k < 32; ++k) s += rowloss[threadIdx.x + 256 * k];
#pragma unroll
        for (int off = 32; off > 0; off >>= 1) s += __shfl_down(s, off);
        if (lane == 0) red[w] = s;
        __syncthreads();
        if (threadIdx.x == 0)
            *outloss = 1.25f * (red[0] + red[1] + red[2] + red[3]) / (float)(BB * ED * TT);
    }
}

// ---------------------------------------------------------------------------
extern "C" void kernel_launch(void* const* d_in, const int* in_sizes, int n_in,
                              void* d_out, int out_size, void* d_ws, size_t ws_size,
                              hipStream_t stream)
{
    const float* z   = (const float*)d_in[0];
    const int*   dom = (const int*)d_in[1];
    const float* emb = (const float*)d_in[3];
    const float* pw  = (const float*)d_in[4];
    const float* pb  = (const float*)d_in[5];
    float* out = (float*)d_out;

    char* p = (char*)d_ws;
    _Float16* Zh = (_Float16*)p;            p += (size_t)MM * 512 * 2;   // 8 MB
    float*    Zt = (float*)p;               p += (size_t)MM * 512 * 4;   // 16 MB
    _Float16* Eb = (_Float16*)p;            p += (size_t)NE * 1024 * 2;  // 16 MB
    _Float16* Wb = (_Float16*)p;            p += (size_t)ED * 1024 * 2;  // 1 MB
    float*    cb = (float*)p;               p += (size_t)NE * 512 * 4;   // 16 MB
    _Float16* Ch = (_Float16*)p;            p += (size_t)NE * 512 * 2;   // 8 MB
    float* cnorm = (float*)p;               p += (size_t)(NE + 2) * 4;   // 32 KB (+legacy scalars)
    _Float16* bmin = (_Float16*)p;          p += (size_t)MM * 2048 * 2;  // 32 MB
    int*   minidx = (int*)p;                p += (size_t)MM * 4;         // 32 KB
    float* rowloss = (float*)p;                                          // 32 KB

    k_prep   <<<1024 + (NE + ED) / 2 + 9, 256, 0, stream>>>(z, emb, pw, Zh, Zt, Eb, Wb, cnorm);
    k_cb     <<<dim3(512), 256, 0, stream>>>(Eb, Wb, pb, cb, Ch, cnorm);
    k_coarse <<<dim3(64, 64), 256, 0, stream>>>(Zh, Ch, cnorm, dom, bmin);
    k_refine <<<MM / 4, 256, 0, stream>>>(Zt, cb, cnorm, bmin, dom, minidx,
                                          out + (size_t)NE * ED, rowloss);
    k_zq     <<<dim3(4, 16, 8), 256, 0, stream>>>(cb, minidx, rowloss, out,
                                                  out + (size_t)NE * ED + MM);
}

// Round 14
// 189.517 us; speedup vs baseline: 1.0173x; 1.0173x over previous
//
#include <hip/hip_runtime.h>
#include <math.h>

#define NE   8192
#define ED   512
#define BB   8
#define TT   1024
#define MM   (BB*TT)

#define FLT_BIG 3.402823466e38f
#define MARGIN  0.08f

typedef _Float16 half8 __attribute__((ext_vector_type(8)));
typedef _Float16 half4 __attribute__((ext_vector_type(4)));
typedef float    floatx4 __attribute__((ext_vector_type(4)));

typedef __attribute__((address_space(3))) unsigned int       lds_u32;
typedef const __attribute__((address_space(1))) unsigned int gbl_u32;

__device__ __forceinline__ void async_copy16(void* lds, const void* g) {
    __builtin_amdgcn_global_load_lds((gbl_u32*)(unsigned long long)g,
                                     (lds_u32*)(unsigned long long)lds,
                                     16, 0, 0);
}

// ---------------------------------------------------------------------------
// K0 (fused prep): blocks 0..1023 transpose z -> Zh (f16 4z) + Zt (fp32 rows);
// blocks 1024..5375 convert emb/pw -> hi/lo f16; blocks 5376..5384 zero
// cnorm (+legacy scalars). (bmin needs NO init: refine only reads the
// domain-valid unit slice, which valid coarse blocks always write.)
// ---------------------------------------------------------------------------
__global__ __launch_bounds__(256) void k_prep(
    const float* __restrict__ z, const float* __restrict__ emb,
    const float* __restrict__ pw, _Float16* __restrict__ Zh,
    float* __restrict__ Zt, _Float16* __restrict__ Eb,
    _Float16* __restrict__ Wb, float* __restrict__ cnorm)
{
    const int bid = blockIdx.x;
    const int tid = threadIdx.x;
    if (bid < 1024) {
        __shared__ float T[64][68];
        const int ct = bid & 7, tt = (bid >> 3) & 15, b = bid >> 7;
        const int f4 = tid & 15;
        const int c0 = tid >> 4;
#pragma unroll
        for (int r = 0; r < 4; ++r) {
            const int c = c0 + r * 16;
            const float4 v = *(const float4*)(z + ((size_t)(b * ED + ct * 64 + c)) * TT + tt * 64 + f4 * 4);
            T[f4*4+0][c] = v.x; T[f4*4+1][c] = v.y;
            T[f4*4+2][c] = v.z; T[f4*4+3][c] = v.w;
        }
        __syncthreads();
        {   // f16 hi write
            const int tl = tid >> 2, q = tid & 3;
            const size_t m = (size_t)b * TT + tt * 64 + tl;
            _Float16* outh = Zh + m * 512 + ct * 64 + q * 16;
#pragma unroll
            for (int g = 0; g < 2; ++g) {
                half8 hv;
#pragma unroll
                for (int jj = 0; jj < 8; ++jj)
                    hv[jj] = (_Float16)(4.0f * T[tl][q*16 + g*8 + jj]);
                *(half8*)(outh + g * 8) = hv;
            }
        }
        {   // fp32 transposed write
            const int tl2 = tid >> 4;
            const int c4 = (tid & 15) * 4;
#pragma unroll
            for (int it = 0; it < 4; ++it) {
                const int t_local = tl2 + it * 16;
                const float4 v = *(const float4*)&T[t_local][c4];
                *(float4*)(Zt + ((size_t)b * TT + tt * 64 + t_local) * 512 + ct * 64 + c4) = v;
            }
        }
    } else if (bid < 5376) {
        const int g = (bid - 1024) * 256 + tid;
        const int row = g >> 7, c4 = (g & 127) * 4;
        const float* src;
        _Float16* dst;
        if (row < NE) { src = emb + (size_t)row * 512;        dst = Eb + (size_t)row * 1024; }
        else          { src = pw + (size_t)(row - NE) * 512;  dst = Wb + (size_t)(row - NE) * 1024; }
        const float4 v = *(const float4*)(src + c4);
        half4 h, l;
        const float s[4] = {v.x * 64.0f, v.y * 64.0f, v.z * 64.0f, v.w * 64.0f};
#pragma unroll
        for (int j = 0; j < 4; ++j) {
            const _Float16 hh = (_Float16)s[j];
            h[j] = hh;
            l[j] = (_Float16)(s[j] - (float)hh);
        }
        *(half4*)(dst + c4) = h;
        *(half4*)(dst + 512 + c4) = l;
    } else {
        const int zidx = bid - 5376;          // 0..8
        if (zidx < 8) {
            ((float4*)cnorm)[zidx * 256 + tid] = make_float4(0.f, 0.f, 0.f, 0.f);
        } else if (tid == 0) {
            cnorm[NE] = 0.0f;
            ((unsigned int*)cnorm)[NE + 1] = 0u;
        }
    }
}

// ---------------------------------------------------------------------------
// K1: codebook GEMM, fused-term staging; 128n x 64d tiles, 256 threads,
// Eb-locality XCD remap (r13, neutral but kept: equal within noise, better
// L2 citizenship).
// ---------------------------------------------------------------------------
#define S_AH 0
#define S_AL 8192
#define S_BH 16384
#define S_BL 20480
__global__ __launch_bounds__(256) void k_cb(
    const _Float16* __restrict__ Eb, const _Float16* __restrict__ Wb,
    const float* __restrict__ pb, float* __restrict__ cb,
    _Float16* __restrict__ Ch, float* __restrict__ cnorm)
{
    __shared__ __align__(16) _Float16 S[24576];   // Ah(16K)|Al(16K)|Bh(8K)|Bl(8K) bytes

    const int tid = threadIdx.x;
    const int wave = tid >> 6, lane = tid & 63;
    const int L = blockIdx.x;
    const int n0 = (((L >> 6) * 8) + (L & 7)) * 128;
    const int d0 = ((L >> 3) & 7) * 64;
    const int wm = wave >> 1, wn = wave & 1;      // 2x2 waves -> 64 codes x 32 d
    const int lm = lane & 15, lq = lane >> 4;

    floatx4 acc[4][2];
#pragma unroll
    for (int i = 0; i < 4; ++i)
#pragma unroll
        for (int j = 0; j < 2; ++j) acc[i][j] = (floatx4)0.0f;

    for (int lc = 0; lc < 8; ++lc) {
        const int kc = lc * 64;
        __syncthreads();
#pragma unroll
        for (int r = 0; r < 12; ++r) {            // 48 spans of 1KB
            const int s = wave * 12 + r;
            const int row8 = lane >> 3;
            const int srcx = lane & 7;
            if (s < 16) {
                const int row = s * 8 + row8;
                const int src = srcx ^ (row & 7);
                async_copy16(&S[S_AH + s * 512], Eb + (size_t)(n0 + row) * 1024 + kc + src * 8);
            } else if (s < 32) {
                const int s2 = s - 16;
                const int row = s2 * 8 + row8;
                const int src = srcx ^ (row & 7);
                async_copy16(&S[S_AL + s2 * 512], Eb + (size_t)(n0 + row) * 1024 + 512 + kc + src * 8);
            } else if (s < 40) {
                const int s2 = s - 32;
                const int row = s2 * 8 + row8;
                const int src = srcx ^ (row & 7);
                async_copy16(&S[S_BH + s2 * 512], Wb + (size_t)(d0 + row) * 1024 + kc + src * 8);
            } else {
                const int s2 = s - 40;
                const int row = s2 * 8 + row8;
                const int src = srcx ^ (row & 7);
                async_copy16(&S[S_BL + s2 * 512], Wb + (size_t)(d0 + row) * 1024 + 512 + kc + src * 8);
            }
        }
        __syncthreads();

#pragma unroll
        for (int ks = 0; ks < 2; ++ks) {
            half8 ah[4], al[4], bh[2], bl[2];
#pragma unroll
            for (int i = 0; i < 4; ++i) {
                const int row = wm * 64 + i * 16 + lm;
                const int slot = (ks * 4 + lq) ^ (row & 7);
                ah[i] = *(const half8*)&S[S_AH + row * 64 + slot * 8];
                al[i] = *(const half8*)&S[S_AL + row * 64 + slot * 8];
            }
#pragma unroll
            for (int j = 0; j < 2; ++j) {
                const int row = wn * 32 + j * 16 + lm;
                const int slot = (ks * 4 + lq) ^ (row & 7);
                bh[j] = *(const half8*)&S[S_BH + row * 64 + slot * 8];
                bl[j] = *(const half8*)&S[S_BL + row * 64 + slot * 8];
            }
#pragma unroll
            for (int i = 0; i < 4; ++i)
#pragma unroll
                for (int j = 0; j < 2; ++j) {
                    acc[i][j] = __builtin_amdgcn_mfma_f32_16x16x32_f16(ah[i], bh[j], acc[i][j], 0, 0, 0);
                    acc[i][j] = __builtin_amdgcn_mfma_f32_16x16x32_f16(ah[i], bl[j], acc[i][j], 0, 0, 0);
                    acc[i][j] = __builtin_amdgcn_mfma_f32_16x16x32_f16(al[i], bh[j], acc[i][j], 0, 0, 0);
                }
        }
    }

    float bias[2];
#pragma unroll
    for (int j = 0; j < 2; ++j) bias[j] = pb[d0 + wn * 32 + j * 16 + lm];

    float nsum[16];
#pragma unroll
    for (int p = 0; p < 16; ++p) nsum[p] = 0.0f;

#pragma unroll
    for (int i = 0; i < 4; ++i) {
#pragma unroll
        for (int j = 0; j < 2; ++j) {
            const int d = d0 + wn * 32 + j * 16 + lm;
#pragma unroll
            for (int r = 0; r < 4; ++r) {
                const float v = acc[i][j][r] * 0.000244140625f + bias[j];  // 1/4096
                const int n = n0 + wm * 64 + i * 16 + lq * 4 + r;
                cb[(size_t)n * 512 + d] = v;
                Ch[(size_t)n * 512 + d] = (_Float16)(v * 64.0f);
                nsum[i * 4 + r] += v * v;
            }
        }
    }
#pragma unroll
    for (int stp = 1; stp < 16; stp <<= 1) {
#pragma unroll
        for (int p = 0; p < 16; ++p) nsum[p] += __shfl_xor(nsum[p], stp);
    }
    float myv = nsum[0];
#pragma unroll
    for (int p = 1; p < 16; ++p) if (lm == p) myv = nsum[p];
    const int n = n0 + wm * 64 + (lm >> 2) * 16 + lq * 4 + (lm & 3);
    atomicAdd(&cnorm[n], myv);
}

// ---------------------------------------------------------------------------
// K2: coarse distance GEMM (hi-only, K=512). SAME 128x128 tile & schedule
// as r3 (counted-vmcnt 2-phase, XCD swizzle, setprio), but 512 THREADS
// (8 waves, 4 wm x 2 wn): per-wave 32 codes x 64 z (acc[2][4]) -> LDS
// unchanged (2 blocks/CU) but 16 waves/CU = 4 waves/SIMD (was 2) -- TLP to
// absorb the per-chunk stage+wait+barrier stall (m114 co-scheduling).
// Staging 4 loads/lane, counted wait vmcnt(4). Math/bmin layout identical.
// ---------------------------------------------------------------------------
__global__ __launch_bounds__(512) void k_coarse(
    const _Float16* __restrict__ Zh, const _Float16* __restrict__ Ch,
    const float* __restrict__ cnorm, const int* __restrict__ dom_arr,
    _Float16* __restrict__ bmin)
{
    const int f   = blockIdx.y * 64 + blockIdx.x;
    const int xcd = f & 7;
    const int idx = f >> 3;
    const int mt  = idx >> 3;                 // z-tile 0..63
    const int nt  = (idx & 7) * 8 + xcd;      // code-tile 0..63
    const int b = mt >> 3;
    const int dom = dom_arr[b];
    const int chunk = nt >> 4;
    const bool valid = (dom == 3) || (dom == 0 && chunk == 0) ||
                       (dom == 1 && chunk == 1) || (dom == 2 && chunk >= 2);
    if (!valid) return;

    const int tid = threadIdx.x;
    const int m0 = mt * 128, n0 = nt * 128;

    __shared__ __align__(16) _Float16 As[2][128 * 64];   // codes (As[0] reused as bs)
    __shared__ __align__(16) _Float16 Bs[2][128 * 64];   // z
    __shared__ __align__(16) float cnLds[128];

    const int wave = tid >> 6, lane = tid & 63;
    const int wm = wave >> 1, wn = wave & 1;   // 4x2: wm code-quarter, wn z-half
    const int lm = lane & 15, lq = lane >> 4;

    floatx4 acc[2][4];
#pragma unroll
    for (int i = 0; i < 2; ++i)
#pragma unroll
        for (int j = 0; j < 4; ++j) acc[i][j] = (floatx4)0.0f;

#define STAGE_K(buf, lc_) do {                                                  \
        const int kk0_ = (lc_) * 64;                                            \
        _Pragma("unroll")                                                       \
        for (int r_ = 0; r_ < 2; ++r_) {                                        \
            const int s_ = wave * 2 + r_;                                       \
            const int row_ = s_ * 8 + (lane >> 3);                              \
            const int src_ = (lane & 7) ^ (row_ & 7);                           \
            async_copy16(&As[buf][s_ * 512], Ch + (size_t)(n0 + row_) * 512 + kk0_ + src_ * 8); \
            async_copy16(&Bs[buf][s_ * 512], Zh + (size_t)(m0 + row_) * 512 + kk0_ + src_ * 8); \
        } } while (0)

    // prologue: stage chunk 0 (+cnorm on wave0; issued after chunk-0 loads,
    // so the first counted wait vmcnt(4) drains it along with chunk 0)
    STAGE_K(0, 0);
    if (wave == 0 && lane < 32)
        async_copy16(&cnLds[0], cnorm + n0 + lane * 4);

    for (int lc = 0; lc < 8; ++lc) {
        const int cur = lc & 1;
        if (lc < 7) {
            STAGE_K(cur ^ 1, lc + 1);   // 4 more loads in flight (8 outstanding)
            asm volatile("s_waitcnt vmcnt(4)" ::: "memory");
        } else {
            asm volatile("s_waitcnt vmcnt(0)" ::: "memory");
        }
        __builtin_amdgcn_s_barrier();    // all waves' chunk-lc loads landed
        asm volatile("" ::: "memory");

        __builtin_amdgcn_s_setprio(1);
#pragma unroll
        for (int ks = 0; ks < 2; ++ks) {
            half8 af[2], bf[4];
#pragma unroll
            for (int i = 0; i < 2; ++i) {
                const int row = wm * 32 + i * 16 + lm;            // code row
                const int slot = (ks * 4 + lq) ^ (row & 7);
                af[i] = *(const half8*)&As[cur][row * 64 + slot * 8];
            }
#pragma unroll
            for (int j = 0; j < 4; ++j) {
                const int row = wn * 64 + j * 16 + lm;            // z row
                const int slot = (ks * 4 + lq) ^ (row & 7);
                bf[j] = *(const half8*)&Bs[cur][row * 64 + slot * 8];
            }
#pragma unroll
            for (int i = 0; i < 2; ++i)
#pragma unroll
                for (int j = 0; j < 4; ++j)
                    acc[i][j] = __builtin_amdgcn_mfma_f32_16x16x32_f16(af[i], bf[j], acc[i][j], 0, 0, 0);
        }
        __builtin_amdgcn_s_setprio(0);
        asm volatile("" ::: "memory");
        __builtin_amdgcn_s_barrier();    // all waves done READING buf[cur]
    }
#undef STAGE_K

    // D layout: row (code) = wm*32 + i*16 + lq*4 + r, col (z) = wn*64 + j*16 + lm
    float cnv[2][4];
#pragma unroll
    for (int i = 0; i < 2; ++i)
#pragma unroll
        for (int r = 0; r < 4; ++r)
            cnv[i][r] = cnLds[wm * 32 + i * 16 + lq * 4 + r];

    // 4-code unit minima: fully in-lane over the r-quad
    float um[2][4];
#pragma unroll
    for (int i = 0; i < 2; ++i) {
#pragma unroll
        for (int j = 0; j < 4; ++j) {
            float m01 = fminf(cnv[i][0] - acc[i][j][0] * 0.0078125f,
                              cnv[i][1] - acc[i][j][1] * 0.0078125f);
            float m23 = fminf(cnv[i][2] - acc[i][j][2] * 0.0078125f,
                              cnv[i][3] - acc[i][j][3] * 0.0078125f);
            um[i][j] = fminf(m01, m23);
        }
    }

    // loop-final barrier separates all As reads from this aliasing write
    _Float16 (*bs)[40] = (_Float16(*)[40])&As[0][0];   // [m_local][unit 0..31]
#pragma unroll
    for (int i = 0; i < 2; ++i)
#pragma unroll
        for (int j = 0; j < 4; ++j)
            bs[wn * 64 + j * 16 + lm][wm * 8 + i * 4 + lq] = (_Float16)um[i][j];
    __syncthreads();
    {   // writeout: 128 rows x 32 units, 512 threads x 8 halfwords
        const int r = tid >> 2, h = tid & 3;
        half8 v;
#pragma unroll
        for (int k = 0; k < 8; ++k) v[k] = bs[r][h * 8 + k];
        *(half8*)(bmin + (size_t)(m0 + r) * 2048 + nt * 32 + h * 8) = v;
    }
}

// ---------------------------------------------------------------------------
// K3: refine (r12 structure). One wave per z-row, no block barrier.
// Register-resident um via unrolled-with-guard loops; LDS candidate queue
// (ballot+rank, original (g,j,L) order); pairwise rescore with 8 parallel
// FMA/shuffle chains. Lane 0 writes rowloss[m] = bestv + ||z||^2.
// ---------------------------------------------------------------------------
__global__ __launch_bounds__(256) void k_refine(
    const float* __restrict__ Zt, const float* __restrict__ cb,
    const float* __restrict__ cnorm, const _Float16* __restrict__ bmin,
    const int* __restrict__ dom_arr, int* __restrict__ minidx,
    float* __restrict__ out_idx, float* __restrict__ rowloss)
{
    __shared__ unsigned short queue[4][2048];
    const int wv = threadIdx.x >> 6;
    const int m = blockIdx.x * 4 + wv;
    const int lane = threadIdx.x & 63;
    const int b = m >> 10;
    const int dom = dom_arr[b];
    const int bg = (dom == 0) ? 0 : (dom == 1) ? 1 : (dom == 2) ? 2 : 0;
    const int ng = (dom == 2) ? 2 : (dom == 3) ? 4 : 1;

    const _Float16* brow = bmin + (size_t)m * 2048;
    float um[4][8];
#pragma unroll
    for (int g = 0; g < 4; ++g) {
        if (g < ng) {
            const half8 u = *(const half8*)(brow + (bg + g) * 512 + lane * 8);
#pragma unroll
            for (int j = 0; j < 8; ++j) um[g][j] = (float)u[j];
        }
    }

    float gmin = FLT_BIG;
#pragma unroll
    for (int g = 0; g < 4; ++g) {
        if (g < ng) {
#pragma unroll
            for (int j = 0; j < 8; ++j) gmin = fminf(gmin, um[g][j]);
        }
    }
#pragma unroll
    for (int s = 32; s > 0; s >>= 1) gmin = fminf(gmin, __shfl_xor(gmin, s));
    const float thr = gmin + MARGIN;

    float zr[8];
#pragma unroll
    for (int j = 0; j < 8; ++j)
        zr[j] = Zt[(size_t)m * 512 + lane + 64 * j];

    // ||z_row||^2 (wave-uniform after butterfly) for the loss
    float rss = 0.f;
#pragma unroll
    for (int j = 0; j < 8; ++j) rss += zr[j] * zr[j];
#pragma unroll
    for (int s = 32; s > 0; s >>= 1) rss += __shfl_xor(rss, s);

    // build candidate queue; order == original (g, j, L-ascending)
    unsigned short* q = &queue[wv][0];
    const unsigned long long lanemask_lt = (lane == 0) ? 0ull : (~0ull >> (64 - lane));
    int cnt = 0;
#pragma unroll
    for (int g = 0; g < 4; ++g) {
        if (g < ng) {
#pragma unroll
            for (int j = 0; j < 8; ++j) {
                const bool hit = (um[g][j] <= thr);
                const unsigned long long mask = __ballot(hit);
                if (hit) {
                    const int rank = __popcll(mask & lanemask_lt);
                    q[cnt + rank] = (unsigned short)((bg + g) * 512 + lane * 8 + j);
                }
                cnt += __popcll(mask);
            }
        }
    }

    float bestv = FLT_BIG; int besti = 0x7FFFFFFF;

    for (int ci = 0; ci < cnt; ci += 2) {
        const int u0 = q[ci];
        const bool has1 = (ci + 1 < cnt);
        const int u1 = has1 ? (int)q[ci + 1] : 0;
        const int nb0 = u0 * 4, nb1 = u1 * 4;
        const float* r0 = cb + (size_t)nb0 * 512 + lane;
        const float* r1 = cb + (size_t)nb1 * 512 + lane;

        float a0 = 0.f, a1 = 0.f, a2 = 0.f, a3 = 0.f;
        float c0 = 0.f, c1 = 0.f, c2 = 0.f, c3 = 0.f;
#pragma unroll
        for (int jj = 0; jj < 8; ++jj) {
            const int o = 64 * jj;
            a0 += zr[jj] * r0[o];
            a1 += zr[jj] * r0[512 + o];
            a2 += zr[jj] * r0[1024 + o];
            a3 += zr[jj] * r0[1536 + o];
        }
        if (has1) {
#pragma unroll
            for (int jj = 0; jj < 8; ++jj) {
                const int o = 64 * jj;
                c0 += zr[jj] * r1[o];
                c1 += zr[jj] * r1[512 + o];
                c2 += zr[jj] * r1[1024 + o];
                c3 += zr[jj] * r1[1536 + o];
            }
        }
#pragma unroll
        for (int s = 32; s > 0; s >>= 1) {
            a0 += __shfl_xor(a0, s); a1 += __shfl_xor(a1, s);
            a2 += __shfl_xor(a2, s); a3 += __shfl_xor(a3, s);
            c0 += __shfl_xor(c0, s); c1 += __shfl_xor(c1, s);
            c2 += __shfl_xor(c2, s); c3 += __shfl_xor(c3, s);
        }
        {
            const float f0 = cnorm[nb0]     - 2.0f * a0;
            const float f1 = cnorm[nb0 + 1] - 2.0f * a1;
            const float f2 = cnorm[nb0 + 2] - 2.0f * a2;
            const float f3 = cnorm[nb0 + 3] - 2.0f * a3;
            if (f0 < bestv || (f0 == bestv && nb0     < besti)) { bestv = f0; besti = nb0;     }
            if (f1 < bestv || (f1 == bestv && nb0 + 1 < besti)) { bestv = f1; besti = nb0 + 1; }
            if (f2 < bestv || (f2 == bestv && nb0 + 2 < besti)) { bestv = f2; besti = nb0 + 2; }
            if (f3 < bestv || (f3 == bestv && nb0 + 3 < besti)) { bestv = f3; besti = nb0 + 3; }
        }
        if (has1) {
            const float f0 = cnorm[nb1]     - 2.0f * c0;
            const float f1 = cnorm[nb1 + 1] - 2.0f * c1;
            const float f2 = cnorm[nb1 + 2] - 2.0f * c2;
            const float f3 = cnorm[nb1 + 3] - 2.0f * c3;
            if (f0 < bestv || (f0 == bestv && nb1     < besti)) { bestv = f0; besti = nb1;     }
            if (f1 < bestv || (f1 == bestv && nb1 + 1 < besti)) { bestv = f1; besti = nb1 + 1; }
            if (f2 < bestv || (f2 == bestv && nb1 + 2 < besti)) { bestv = f2; besti = nb1 + 2; }
            if (f3 < bestv || (f3 == bestv && nb1 + 3 < besti)) { bestv = f3; besti = nb1 + 3; }
        }
    }
    if (lane == 0) {
        minidx[m] = besti;
        out_idx[m] = (float)besti;
        rowloss[m] = bestv + rss;   // exact ||c-z||^2 for this row
    }
}

// ---------------------------------------------------------------------------
// K4: z_q gather + transpose via LDS (coalesced cb reads, coalesced outz
// writes; LDS pitch 129 -> conflict-free). Block (0,0,0) reduces
// rowloss[8192] -> outloss.
// ---------------------------------------------------------------------------
__global__ __launch_bounds__(256) void k_zq(
    const float* __restrict__ cb, const int* __restrict__ minidx,
    const float* __restrict__ rowloss, float* __restrict__ outz,
    float* __restrict__ outloss)
{
    __shared__ float Tz[64][129];
    const int cc = blockIdx.x, tt = blockIdx.y, b = blockIdx.z;
    const int lane = threadIdx.x & 63;
    const int w = threadIdx.x >> 6;

    // stage: wave w loads rows w*16..w*16+15, each row slice coalesced
#pragma unroll 4
    for (int r = 0; r < 16; ++r) {
        const int row = w * 16 + r;
        const int idx = minidx[b * TT + tt * 64 + row];      // wave-uniform
        const float2 v = *(const float2*)(cb + (size_t)idx * 512 + cc * 128 + lane * 2);
        Tz[row][lane * 2]     = v.x;
        Tz[row][lane * 2 + 1] = v.y;
    }
    __syncthreads();

    // write: lanes sweep t (contiguous per instr); 32 c's per thread
    const int t = tt * 64 + lane;
#pragma unroll 8
    for (int k = 0; k < 32; ++k) {
        const int cl = w * 32 + k;
        outz[((size_t)(b * ED + cc * 128 + cl)) * TT + t] = Tz[lane][cl];
    }

    if (cc == 0 && tt == 0 && b == 0) {
        __shared__ float red[4];
        float s = 0.f;
#pragma unroll
        for (int k = 0; k < 32; ++k) s += rowloss[threadIdx.x + 256 * k];
#pragma unroll
        for (int off = 32; off > 0; off >>= 1) s += __shfl_down(s, off);
        if (lane == 0) red[w] = s;
        __syncthreads();
        if (threadIdx.x == 0)
            *outloss = 1.25f * (red[0] + red[1] + red[2] + red[3]) / (float)(BB * ED * TT);
    }
}

// ---------------------------------------------------------------------------
extern "C" void kernel_launch(void* const* d_in, const int* in_sizes, int n_in,
                              void* d_out, int out_size, void* d_ws, size_t ws_size,
                              hipStream_t stream)
{
    const float* z   = (const float*)d_in[0];
    const int*   dom = (const int*)d_in[1];
    const float* emb = (const float*)d_in[3];
    const float* pw  = (const float*)d_in[4];
    const float* pb  = (const float*)d_in[5];
    float* out = (float*)d_out;

    char* p = (char*)d_ws;
    _Float16* Zh = (_Float16*)p;            p += (size_t)MM * 512 * 2;   // 8 MB
    float*    Zt = (float*)p;               p += (size_t)MM * 512 * 4;   // 16 MB
    _Float16* Eb = (_Float16*)p;            p += (size_t)NE * 1024 * 2;  // 16 MB
    _Float16* Wb = (_Float16*)p;            p += (size_t)ED * 1024 * 2;  // 1 MB
    float*    cb = (float*)p;               p += (size_t)NE * 512 * 4;   // 16 MB
    _Float16* Ch = (_Float16*)p;            p += (size_t)NE * 512 * 2;   // 8 MB
    float* cnorm = (float*)p;               p += (size_t)(NE + 2) * 4;   // 32 KB (+legacy scalars)
    _Float16* bmin = (_Float16*)p;          p += (size_t)MM * 2048 * 2;  // 32 MB
    int*   minidx = (int*)p;                p += (size_t)MM * 4;         // 32 KB
    float* rowloss = (float*)p;                                          // 32 KB

    k_prep   <<<1024 + (NE + ED) / 2 + 9, 256, 0, stream>>>(z, emb, pw, Zh, Zt, Eb, Wb, cnorm);
    k_cb     <<<dim3(512), 256, 0, stream>>>(Eb, Wb, pb, cb, Ch, cnorm);
    k_coarse <<<dim3(64, 64), 512, 0, stream>>>(Zh, Ch, cnorm, dom, bmin);
    k_refine <<<MM / 4, 256, 0, stream>>>(Zt, cb, cnorm, bmin, dom, minidx,
                                          out + (size_t)NE * ED, rowloss);
    k_zq     <<<dim3(4, 16, 8), 256, 0, stream>>>(cb, minidx, rowloss, out,
                                                  out + (size_t)NE * ED + MM);
}